// Round 8
// baseline (118.161 us; speedup 1.0000x reference)
//
#include <hip/hip_runtime.h>

// Event-to-image: B=16, N=500000 events (t,x,y,p) f32 -> (16,720,1280,3) f32.
// Last-event-wins per pixel: p==1 -> (0,255,255); p==0 -> (255,0,255);
// untouched -> (255,255,510). Order-independent via max over
// key = ((event_idx+1)<<1)|p, packed pk = x<<20 | key (31 bits).
//
// R8 = R6 structure (two-pass scatter + LDS stage + coalesced chunk write;
// R7's direct scattered stores + 512-thread blocks regressed) with the block
// tile halved: EVPB=4096 -> LDS 21.7KB -> 7 blocks/CU = 28 waves/CU (was 16).
// Scatter is latency-bound (VALUBusy 3%, BW 29%), so occupancy is the lever.
// Pass 1 reads only y (scalar dword, same cache lines, primes L2/L3);
// pass 2 re-reads full events nontemporally (last use).

#define WIDTH   1280
#define HEIGHT  720
#define BATCH   16
#define NEV     500000
#define THREADS 256
#define EPT     16
#define EVPB    (THREADS * EPT)             // 4096 events per block
#define BPB     ((NEV + EVPB - 1) / EVPB)   // 123 blocks per batch
#define NBLK    (BATCH * BPB)               // 1968
#define PH      (HEIGHT + 1)                // 721 prefix entries per block

typedef float f4 __attribute__((ext_vector_type(4)));

// ws layout: [0, NBLK*PH*4)=pref_g (5.7 MB); [0x800000, +NBLK*EVPB*4)=bins (32.3 MB)

__global__ __launch_bounds__(THREADS) void scatter_k(const float4* __restrict__ ev,
                                                     unsigned int* __restrict__ pref_g,
                                                     unsigned int* __restrict__ bins) {
    __shared__ unsigned int hist[HEIGHT];
    __shared__ unsigned int offs[HEIGHT];
    __shared__ unsigned int wtot[4];
    __shared__ unsigned int stage[EVPB];     // 16 KB

    int t = threadIdx.x;
    int batch = blockIdx.x / BPB;
    int blk   = blockIdx.x % BPB;
    int ev0   = blk * EVPB;
    int cnt   = NEV - ev0; if (cnt > EVPB) cnt = EVPB;
    const float4* bev = ev + (size_t)batch * NEV + ev0;
    const f4* bevv = (const f4*)bev;
    const float* yb = (const float*)bev + 2;          // y component, stride 4 floats

    for (int r = t; r < HEIGHT; r += THREADS) hist[r] = 0u;
    __syncthreads();

    // pass 1: scalar y loads (normal -> primes L2/L3 for pass 2), histogram
    for (int k = 0; k < EPT; ++k) {
        int e = t + k * THREADS;
        if (e < cnt)
            atomicAdd(&hist[(int)yb[4 * e]], 1u);
    }
    __syncthreads();

    // exclusive prefix over 720 rows: threads 0..239 own 3 rows; shfl wave scan
    unsigned int own = 0u;
    int b3 = t * 3;
    if (t < 240) own = hist[b3] + hist[b3 + 1] + hist[b3 + 2];
    unsigned int incl = own;
    for (int d = 1; d < 64; d <<= 1) {
        unsigned int n = __shfl_up(incl, d);
        if ((t & 63) >= d) incl += n;
    }
    if ((t & 63) == 63) wtot[t >> 6] = incl;
    __syncthreads();
    unsigned int wbase = 0u;
    for (int w = 0; w < (t >> 6); ++w) wbase += wtot[w];
    unsigned int total = wtot[0] + wtot[1] + wtot[2] + wtot[3];   // == cnt
    if (t < 240) {
        unsigned int run = wbase + incl - own;
        offs[b3] = run;      run += hist[b3];
        offs[b3 + 1] = run;  run += hist[b3 + 1];
        offs[b3 + 2] = run;
    }
    __syncthreads();

    // publish per-block row prefix BEFORE pass 2 mutates offs
    unsigned int* pg = pref_g + (size_t)blockIdx.x * PH;
    for (int r = t; r < PH; r += THREADS)
        pg[r] = (r < HEIGHT) ? offs[r] : total;
    __syncthreads();

    // pass 2: nt re-read (L2/L3 hit, last use), rank, place sorted into stage
    for (int k = 0; k < EPT; ++k) {
        int e = t + k * THREADS;
        if (e < cnt) {
            f4 v = __builtin_nontemporal_load(&bevv[e]);
            int xi = (int)v.y;
            int yi = (int)v.z;
            unsigned int pbit = (v.w == 1.0f) ? 1u : 0u;
            unsigned int key  = (((unsigned int)(ev0 + e) + 1u) << 1) | pbit;  // 20 bits
            unsigned int pk   = ((unsigned int)xi << 20) | key;
            unsigned int slot = atomicAdd(&offs[yi], 1u);                      // < cnt
            stage[slot] = pk;
        }
    }
    __syncthreads();

    // write the sorted chunk, fully coalesced (keep in L2/L3 for render)
    uint4* dst = (uint4*)(bins + (size_t)blockIdx.x * EVPB);
    const uint4* src = (const uint4*)stage;
    for (int k = t; k < EVPB / 4; k += THREADS)
        dst[k] = src[k];
}

__global__ __launch_bounds__(THREADS) void render_k(const unsigned int* __restrict__ pref_g,
                                                    const unsigned int* __restrict__ bins,
                                                    float4* __restrict__ out) {
    __shared__ unsigned int win[WIDTH];
    __shared__ unsigned int segbase[BPB];
    __shared__ unsigned int segpref[132];    // [0..123] used; pad for lanes 124..127
    __shared__ unsigned int swtot;

    int t = threadIdx.x;
    int rowid = blockIdx.x;                  // batch*720 + y
    int batch = rowid / HEIGHT;
    int r     = rowid - batch * HEIGHT;

    for (int x = t; x < WIDTH; x += THREADS) win[x] = 0u;

    unsigned int mycnt = 0u;
    if (t < BPB) {
        const unsigned int* pg = pref_g + (size_t)(batch * BPB + t) * PH + r;
        unsigned int p0 = pg[0], p1 = pg[1];
        segbase[t] = (unsigned int)((batch * BPB + t) * EVPB) + p0;
        mycnt = p1 - p0;
    }
    if (t < 128) {                           // 2-wave inclusive scan of 123 counts
        unsigned int v = mycnt;
        for (int d = 1; d < 64; d <<= 1) {
            unsigned int n = __shfl_up(v, d);
            if ((t & 63) >= d) v += n;
        }
        if (t == 63) swtot = v;              // wave-0 total
        __syncthreads();                     // all 256 threads reach this
        if (t >= 64) v += swtot;
        if (t == 0) segpref[0] = 0u;
        segpref[t + 1] = v;
    } else {
        __syncthreads();
    }
    __syncthreads();

    unsigned int total = segpref[BPB];       // ~694
    for (unsigned int j = t; j < total; j += THREADS) {
        int lo = 0, hi = BPB - 1;            // largest s with segpref[s] <= j
        while (lo < hi) {
            int mid = (lo + hi + 1) >> 1;
            if (segpref[mid] <= j) lo = mid; else hi = mid - 1;
        }
        unsigned int pk = bins[segbase[lo] + (j - segpref[lo])];
        atomicMax(&win[pk >> 20], pk & 0xFFFFFu);   // LDS atomic
    }
    __syncthreads();

    // write one image row: 1280 px * 3 ch = 960 float4, coalesced, nontemporal
    f4* orow = (f4*)(out + (size_t)rowid * (WIDTH * 3 / 4));
    for (int j = t; j < WIDTH * 3 / 4; j += THREADS) {
        float vals[4];
#pragma unroll
        for (int c = 0; c < 4; ++c) {
            int fi = j * 4 + c;
            int px = fi / 3;
            int ch = fi - px * 3;
            unsigned int k = win[px];
            float val;
            if (k == 0u) val = (ch == 2) ? 510.0f : 255.0f;
            else if (ch == 2) val = 255.0f;
            else if (ch == 0) val = (k & 1u) ? 0.0f : 255.0f;
            else              val = (k & 1u) ? 255.0f : 0.0f;
            vals[c] = val;
        }
        f4 o = { vals[0], vals[1], vals[2], vals[3] };
        __builtin_nontemporal_store(o, orow + j);
    }
}

extern "C" void kernel_launch(void* const* d_in, const int* in_sizes, int n_in,
                              void* d_out, int out_size, void* d_ws, size_t ws_size,
                              hipStream_t stream) {
    const float4* ev = (const float4*)d_in[0];
    unsigned int* pref_g = (unsigned int*)d_ws;
    unsigned int* bins   = (unsigned int*)((char*)d_ws + 0x800000);
    float4* out = (float4*)d_out;

    scatter_k<<<NBLK, THREADS, 0, stream>>>(ev, pref_g, bins);
    render_k<<<BATCH * HEIGHT, THREADS, 0, stream>>>(pref_g, bins, out);
}

// Round 9
// 99.683 us; speedup vs baseline: 1.1854x; 1.1854x over previous
//
#include <hip/hip_runtime.h>

// Event-to-image: B=16, N=500000 events (t,x,y,p) f32 -> (16,720,1280,3) f32.
// Last-event-wins per pixel: p==1 -> (0,255,255); p==0 -> (255,0,255);
// untouched -> (255,255,510). Order-independent via max over
// key = ((event_idx+1)<<1)|p, packed pk = x<<20 | key (31 bits).
//
// R9 = R6 scatter (best: 97.8us) UNCHANGED + render's 7-deep LDS-dependent
// binary search replaced by an O(1) segment-lookup table (threads 0..61 fill
// lookup[segpref[t]..segpref[t+1]) with t; gather does ONE LDS read).
// Single-variable round: isolates whether render's serial search was the
// hidden cost (R3 rewrote both kernels at once).

#define WIDTH   1280
#define HEIGHT  720
#define BATCH   16
#define NEV     500000
#define THREADS 256
#define EPT     32
#define EVPB    (THREADS * EPT)             // 8192 events per block
#define BPB     ((NEV + EVPB - 1) / EVPB)   // 62 blocks per batch
#define NBLK    (BATCH * BPB)               // 992
#define PH      (HEIGHT + 1)                // 721 prefix entries per block
#define LUT     1536                        // >= row total (694 +- 26), 32 sigma

typedef float f4 __attribute__((ext_vector_type(4)));

// ws layout: [0, NBLK*PH*4)=pref_g (2.86 MB); [0x400000, +NBLK*EVPB*4)=bins (32.5 MB)

__global__ __launch_bounds__(THREADS) void scatter_k(const float4* __restrict__ ev,
                                                     unsigned int* __restrict__ pref_g,
                                                     unsigned int* __restrict__ bins) {
    __shared__ unsigned int hist[HEIGHT];
    __shared__ unsigned int offs[HEIGHT];
    __shared__ unsigned int wtot[4];
    __shared__ unsigned int stage[EVPB];     // 32 KB

    int t = threadIdx.x;
    int batch = blockIdx.x / BPB;
    int blk   = blockIdx.x % BPB;
    int ev0   = blk * EVPB;
    int cnt   = NEV - ev0; if (cnt > EVPB) cnt = EVPB;
    const float4* bev = ev + (size_t)batch * NEV + ev0;
    const f4* bevv = (const f4*)bev;

    for (int r = t; r < HEIGHT; r += THREADS) hist[r] = 0u;
    __syncthreads();

    // pass 1: row histogram (streams events through L2; pass 2 re-hits)
    for (int k = 0; k < EPT; ++k) {
        int e = t + k * THREADS;
        if (e < cnt) {
            float4 v = bev[e];
            atomicAdd(&hist[(int)v.z], 1u);
        }
    }
    __syncthreads();

    // exclusive prefix over 720 rows: threads 0..239 own 3 rows; shfl wave scan
    unsigned int own = 0u;
    int b3 = t * 3;
    if (t < 240) own = hist[b3] + hist[b3 + 1] + hist[b3 + 2];
    unsigned int incl = own;
    for (int d = 1; d < 64; d <<= 1) {
        unsigned int n = __shfl_up(incl, d);
        if ((t & 63) >= d) incl += n;
    }
    if ((t & 63) == 63) wtot[t >> 6] = incl;
    __syncthreads();
    unsigned int wbase = 0u;
    for (int w = 0; w < (t >> 6); ++w) wbase += wtot[w];
    unsigned int total = wtot[0] + wtot[1] + wtot[2] + wtot[3];   // == cnt
    if (t < 240) {
        unsigned int run = wbase + incl - own;
        offs[b3] = run;      run += hist[b3];
        offs[b3 + 1] = run;  run += hist[b3 + 1];
        offs[b3 + 2] = run;
    }
    __syncthreads();

    // publish per-block row prefix BEFORE pass 2 mutates offs
    unsigned int* pg = pref_g + (size_t)blockIdx.x * PH;
    for (int r = t; r < PH; r += THREADS)
        pg[r] = (r < HEIGHT) ? offs[r] : total;
    __syncthreads();

    // pass 2: re-read (L2 hit; nt = last use) and place sorted into stage
    for (int k = 0; k < EPT; ++k) {
        int e = t + k * THREADS;
        if (e < cnt) {
            f4 v = __builtin_nontemporal_load(&bevv[e]);
            int xi = (int)v.y;
            int yi = (int)v.z;
            unsigned int pbit = (v.w == 1.0f) ? 1u : 0u;
            unsigned int key  = (((unsigned int)(ev0 + e) + 1u) << 1) | pbit;  // 20 bits
            unsigned int pk   = ((unsigned int)xi << 20) | key;
            unsigned int slot = atomicAdd(&offs[yi], 1u);                      // < cnt
            stage[slot] = pk;
        }
    }
    __syncthreads();

    // write the sorted chunk, fully coalesced (keep in L2/L3 for render)
    uint4* dst = (uint4*)(bins + (size_t)blockIdx.x * EVPB);
    const uint4* src = (const uint4*)stage;
    for (int k = t; k < EVPB / 4; k += THREADS)
        dst[k] = src[k];
}

__global__ __launch_bounds__(THREADS) void render_k(const unsigned int* __restrict__ pref_g,
                                                    const unsigned int* __restrict__ bins,
                                                    float4* __restrict__ out) {
    __shared__ unsigned int win[WIDTH];
    __shared__ unsigned int segbase[BPB];
    __shared__ unsigned int segpref[65];
    __shared__ unsigned short lookup[LUT];   // j -> segment id (O(1) gather)

    int t = threadIdx.x;
    int rowid = blockIdx.x;                  // batch*720 + y
    int batch = rowid / HEIGHT;
    int r     = rowid - batch * HEIGHT;

    for (int x = t; x < WIDTH; x += THREADS) win[x] = 0u;

    unsigned int mycnt = 0u;
    if (t < BPB) {
        const unsigned int* pg = pref_g + (size_t)(batch * BPB + t) * PH + r;
        unsigned int p0 = pg[0], p1 = pg[1];
        segbase[t] = (unsigned int)((batch * BPB + t) * EVPB) + p0;
        mycnt = p1 - p0;
    }
    unsigned int mybase = 0u;
    if (t < 64) {                            // wave-0 inclusive scan of 62 counts
        unsigned int v = mycnt;
        for (int d = 1; d < 64; d <<= 1) {
            unsigned int n = __shfl_up(v, d);
            if (t >= d) v += n;
        }
        if (t == 0) segpref[0] = 0u;
        segpref[t + 1] = v;
        mybase = v - mycnt;                  // exclusive
        // fill lookup: ~11 independent LDS stores per thread
        if (t < BPB) {
            unsigned int end = (mybase + mycnt < LUT) ? mybase + mycnt : LUT;
            for (unsigned int j = mybase; j < end; ++j)
                lookup[j] = (unsigned short)t;
        }
    }
    __syncthreads();

    unsigned int total = segpref[BPB];       // ~694
    for (unsigned int j = t; j < total; j += THREADS) {
        int lo;
        if (j < LUT) {
            lo = lookup[j];                  // one LDS read
        } else {                             // impossible in practice; exactness
            lo = 0; int hi = BPB - 1;
            while (lo < hi) {
                int mid = (lo + hi + 1) >> 1;
                if (segpref[mid] <= j) lo = mid; else hi = mid - 1;
            }
        }
        unsigned int pk = bins[segbase[lo] + (j - segpref[lo])];
        atomicMax(&win[pk >> 20], pk & 0xFFFFFu);   // LDS atomic
    }
    __syncthreads();

    // write one image row: 1280 px * 3 ch = 960 float4, coalesced, nontemporal
    f4* orow = (f4*)(out + (size_t)rowid * (WIDTH * 3 / 4));
    for (int j = t; j < WIDTH * 3 / 4; j += THREADS) {
        float vals[4];
#pragma unroll
        for (int c = 0; c < 4; ++c) {
            int fi = j * 4 + c;
            int px = fi / 3;
            int ch = fi - px * 3;
            unsigned int k = win[px];
            float val;
            if (k == 0u) val = (ch == 2) ? 510.0f : 255.0f;
            else if (ch == 2) val = 255.0f;
            else if (ch == 0) val = (k & 1u) ? 0.0f : 255.0f;
            else              val = (k & 1u) ? 255.0f : 0.0f;
            vals[c] = val;
        }
        f4 o = { vals[0], vals[1], vals[2], vals[3] };
        __builtin_nontemporal_store(o, orow + j);
    }
}

extern "C" void kernel_launch(void* const* d_in, const int* in_sizes, int n_in,
                              void* d_out, int out_size, void* d_ws, size_t ws_size,
                              hipStream_t stream) {
    const float4* ev = (const float4*)d_in[0];
    unsigned int* pref_g = (unsigned int*)d_ws;
    unsigned int* bins   = (unsigned int*)((char*)d_ws + 0x400000);
    float4* out = (float4*)d_out;

    scatter_k<<<NBLK, THREADS, 0, stream>>>(ev, pref_g, bins);
    render_k<<<BATCH * HEIGHT, THREADS, 0, stream>>>(pref_g, bins, out);
}